// Round 1
// 300.846 us; speedup vs baseline: 1.1027x; 1.1027x over previous
//
#include <hip/hip_runtime.h>

#define NB 32
#define NA 5
#define NC 80
#define NH 64
#define NW 64
#define MAXT 50
#define CH 85
#define HW (NH*NW)
#define NBLK (NB*NA*HW/256)   /* 2560 blocks */
#define BPB (NA*HW/256)       /* 80 blocks per batch */

__constant__ float c_aw[NA] = {42.3f/32.0f, 102.2f/32.0f, 161.8f/32.0f, 303.1f/32.0f, 359.6f/32.0f};
__constant__ float c_ah[NA] = {55.4f/32.0f, 128.3f/32.0f, 259.2f/32.0f, 154.9f/32.0f, 320.2f/32.0f};

__device__ __forceinline__ float sigm(float x) {
    return __builtin_amdgcn_rcpf(1.0f + __expf(-x));
}

// One fused kernel: per-block target-table build (from tgt directly), base loss
// over this block's 256 cells, and — on the first block of each batch — the
// scattered-cell correction + class term, parallelized 4 lanes per entry.
// Each block writes its partial sum to W[blockIdx.x]; fin sums 2560 partials.
// No atomics, no zeroed-workspace assumption (every slot read is written first).
__global__ __launch_bounds__(256) void fused_kernel(const float* __restrict__ out,
                                                    const float* __restrict__ tgt,
                                                    float* __restrict__ W) {
    const int blk = blockIdx.x;
    const int tid = threadIdx.x;
    const int b   = blk / BPB;            // uniform per block
    const int r   = blk - b*BPB;
    const int a   = r >> 4;               // 16 blocks per (b,a)
    const int ji  = ((r & 15) << 8) + tid;
    const int i   = ji & (NW-1);
    const int j   = ji >> 6;

    __shared__ float sxl[MAXT], sxh[MAXT], syl[MAXT], syh[MAXT], sga[MAXT];
    __shared__ float sgx[MAXT], sgy[MAXT], sgw[MAXT], sgh[MAXT], sgc[MAXT];
    __shared__ int   s_id[MAXT];
    __shared__ int   s_eid[MAXT];
    __shared__ float s_tx[MAXT], s_ty[MAXT], s_tw[MAXT], s_th[MAXT], s_ti[MAXT];
    __shared__ int   s_ec[MAXT];
    __shared__ int   s_nv;
    __shared__ float red[4];

    // ---- phase 0: target tables (wave 0 only; ~50 lanes, trivially cheap) ----
    if (tid < 64) {
        bool iszero = true;
        if (tid < MAXT) {
            const float* p = tgt + (b*MAXT + tid)*5;
            const float gcls = p[0];
            const float rx = p[1];
            iszero = (rx == 0.0f);
            const float gx = rx   * (float)NW;
            const float gy = p[2] * (float)NH;
            const float gw = p[3] * (float)NW;
            const float gh = p[4] * (float)NH;
            sxl[tid] = gx - 0.5f*gw; sxh[tid] = gx + 0.5f*gw;
            syl[tid] = gy - 0.5f*gh; syh[tid] = gy + 0.5f*gh;
            sga[tid] = 0.375f*gw*gh;
            sgx[tid] = gx; sgy[tid] = gy; sgw[tid] = gw; sgh[tid] = gh; sgc[tid] = gcls;
        }
        // valid = cumprod(x != 0): first-zero cutoff; lanes >= MAXT report zero.
        unsigned long long mz = __ballot(iszero);
        if (tid == 0) s_nv = __ffsll(mz) - 1;
    }
    __syncthreads();
    const int nv = s_nv;

    // ---- phase 1: base loss for this block's 256 cells ----
    const size_t base = (size_t)((b*NA + a)*CH)*HW + ji;
    const float ox = out[base];
    const float oy = out[base + HW];
    const float ow = out[base + 2*HW];
    const float oh = out[base + 3*HW];
    const float oc = out[base + 4*HW];

    const float sx = sigm(ox);
    const float sy = sigm(oy);
    const float sc = sigm(oc);
    const float pw = __expf(ow) * c_aw[a];
    const float ph = __expf(oh) * c_ah[a];
    const float px = sx + (float)i;
    const float py = sy + (float)j;
    const float pxl = px - 0.5f*pw, pxh = px + 0.5f*pw;
    const float pyl = py - 0.5f*ph, pyh = py + 0.5f*ph;
    const float pa375 = 0.375f * pw * ph;

    // conf_mask0 test without division:
    // inter/union > 0.6  <=>  max_t(inter_t - 0.375*ga_t) > 0.375*pa
    float m = -1.0f;
    for (int tt = 0; tt < nv; tt++) {
        float iw = fminf(pxh, sxh[tt]) - fmaxf(pxl, sxl[tt]);
        float ih = fminf(pyh, syh[tt]) - fmaxf(pyl, syl[tt]);
        float inter = fmaxf(iw, 0.f) * fmaxf(ih, 0.f);
        m = fmaxf(m, inter - sga[tt]);
    }
    const bool over = m > pa375;

    const float dx = sx - 0.5f, dy = sy - 0.5f;
    float v = dx*dx + dy*dy + ow*ow + oh*oh;
    if (!over) v += sc*sc;
    v *= 0.5f;

    for (int off = 32; off > 0; off >>= 1) v += __shfl_down(v, off);
    if ((tid & 63) == 0) red[tid >> 6] = v;
    __syncthreads();
    float bsum = (tid == 0) ? (red[0] + red[1] + red[2] + red[3]) : 0.0f;

    // ---- phase 2: correction (first block of each batch only; block-uniform) ----
    if (r == 0) {
        // 2a: per-target entry build (wave 0, lane = target)
        if (tid < 64 && tid < nv) {
            const float gx = sgx[tid], gy = sgy[tid], gw = sgw[tid], gh = sgh[tid];
            const float garea = gw * gh;
            float best = -1.0f; int bn = 0;
            #pragma unroll
            for (int n = 0; n < NA; n++) {
                float inter = fminf(gw, c_aw[n]) * fminf(gh, c_ah[n]);
                float uni = garea + c_aw[n]*c_ah[n] - inter;
                float rr = inter / uni;
                if (rr > best) { best = rr; bn = n; }   // first-max wins (argmax)
            }
            int gi = (int)gx; gi = gi < 0 ? 0 : (gi > NW-1 ? NW-1 : gi);
            int gj = (int)gy; gj = gj < 0 ? 0 : (gj > NH-1 ? NH-1 : gj);
            const float awb = c_aw[bn], ahb = c_ah[bn];

            const size_t gbase = (size_t)((b*NA + bn)*CH)*HW + gj*NW + gi;
            const float o0 = out[gbase];
            const float o1 = out[gbase + HW];
            const float o2 = out[gbase + 2*HW];
            const float o3 = out[gbase + 3*HW];
            const float ppx = sigm(o0) + (float)gi;
            const float ppy = sigm(o1) + (float)gj;
            const float ppw = __expf(o2) * awb;
            const float pph = __expf(o3) * ahb;
            const float iw = fminf(gx + 0.5f*gw, ppx + 0.5f*ppw) - fmaxf(gx - 0.5f*gw, ppx - 0.5f*ppw);
            const float ih = fminf(gy + 0.5f*gh, ppy + 0.5f*pph) - fmaxf(gy - 0.5f*gh, ppy - 0.5f*pph);
            const float inter = fmaxf(iw, 0.f) * fmaxf(ih, 0.f);
            const float tiou = inter / (garea + ppw*pph - inter);

            s_id[tid] = (bn*NH + gj)*NW + gi;
            s_tx[tid] = gx - (float)gi;
            s_ty[tid] = gy - (float)gj;
            s_tw[tid] = __logf(gw / awb);
            s_th[tid] = __logf(gh / ahb);
            s_ti[tid] = tiou;
            s_ec[tid] = (int)sgc[tid];
        }
        __syncthreads();
        // parallel last-wins dedup (matches sequential .at[].set)
        if (tid < nv) {
            const int myid = s_id[tid];
            bool keep = true;
            for (int u = tid + 1; u < nv; u++)
                if (s_id[u] == myid) { keep = false; break; }
            s_eid[tid] = keep ? myid : -1;
        }
        __syncthreads();

        // 2b: 4 lanes per entry; channels strided by 4, register-resident.
        float acc = 0.0f;
        const int e = tid >> 2;
        const int q = tid & 3;
        if (e < nv) {
            const int id = s_eid[e];                 // uniform within the 4-lane group
            if (id >= 0) {
                const int ea  = id >> 12;
                const int eji = id & (HW-1);
                const int eii = eji & (NW-1);
                const int ejj = eji >> 6;
                const size_t eb = (size_t)((b*NA + ea)*CH)*HW + eji;
                const float cox = out[eb];
                const float coy = out[eb + HW];
                const float cow = out[eb + 2*HW];
                const float coh = out[eb + 3*HW];
                const float coc = out[eb + 4*HW];
                const float csx = sigm(cox), csy = sigm(coy), csc = sigm(coc);
                const float cpw = __expf(cow) * c_aw[ea];
                const float cph = __expf(coh) * c_ah[ea];
                const float cpx = csx + (float)eii, cpy = csy + (float)ejj;
                const float cxl = cpx - 0.5f*cpw, cxh = cpx + 0.5f*cpw;
                const float cyl = cpy - 0.5f*cph, cyh = cpy + 0.5f*cph;
                const float cpa = 0.375f * cpw * cph;

                // conf_mask0 recompute, nv-loop split across the 4 lanes
                float mm = -1.0f;
                for (int u = q; u < nv; u += 4) {
                    float iw = fminf(cxh, sxh[u]) - fmaxf(cxl, sxl[u]);
                    float ih = fminf(cyh, syh[u]) - fmaxf(cyl, syl[u]);
                    float inter = fmaxf(iw, 0.f) * fmaxf(ih, 0.f);
                    mm = fmaxf(mm, inter - sga[u]);
                }
                mm = fmaxf(mm, __shfl_xor(mm, 1));
                mm = fmaxf(mm, __shfl_xor(mm, 2));

                // logsumexp over 80 classes: 20 channels per lane, one global pass
                const float* lg = out + eb + 5*HW;
                float rch[20];
                #pragma unroll
                for (int k = 0; k < 20; k++) rch[k] = lg[(size_t)(q + 4*k)*HW];
                float mx = rch[0];
                #pragma unroll
                for (int k = 1; k < 20; k++) mx = fmaxf(mx, rch[k]);
                mx = fmaxf(mx, __shfl_xor(mx, 1));
                mx = fmaxf(mx, __shfl_xor(mx, 2));
                float s = 0.0f;
                #pragma unroll
                for (int k = 0; k < 20; k++) s += __expf(rch[k] - mx);
                s += __shfl_xor(s, 1);
                s += __shfl_xor(s, 2);

                if (q == 0) {
                    const float tx = s_tx[e], ty = s_ty[e], tw = s_tw[e], th = s_th[e], ti = s_ti[e];
                    const int cls = s_ec[e];
                    const float dxn = csx - tx, dxo = csx - 0.5f;
                    const float dyn = csy - ty, dyo = csy - 0.5f;
                    const float dwn = cow - tw, dhn = coh - th;
                    float d = dxn*dxn - dxo*dxo + dyn*dyn - dyo*dyo
                            + dwn*dwn - cow*cow + dhn*dhn - coh*coh;
                    float dc = 5.f*(csc - ti)*(csc - ti);
                    if (!(mm > cpa)) dc -= csc*csc;   // base had conf_mask0 * conf^2
                    d += dc;
                    acc += 0.5f * d;
                    acc += mx + __logf(s) - lg[(size_t)cls*HW];
                }
            }
        }
        for (int off = 32; off > 0; off >>= 1) acc += __shfl_down(acc, off);
        if ((tid & 63) == 0) red[tid >> 6] = acc;
        __syncthreads();
        if (tid == 0) bsum += red[0] + red[1] + red[2] + red[3];
    }

    if (tid == 0) W[blk] = bsum;   // partial per block; poison-safe (always written)
}

__global__ __launch_bounds__(256) void fin_kernel(const float* __restrict__ W,
                                                  float* __restrict__ res) {
    float s = 0.0f;
    for (int k = threadIdx.x; k < NBLK; k += 256) s += W[k];
    for (int off = 32; off > 0; off >>= 1) s += __shfl_down(s, off);
    __shared__ float red[4];
    if ((threadIdx.x & 63) == 0) red[threadIdx.x >> 6] = s;
    __syncthreads();
    if (threadIdx.x == 0) res[0] = red[0] + red[1] + red[2] + red[3];
}

extern "C" void kernel_launch(void* const* d_in, const int* in_sizes, int n_in,
                              void* d_out, int out_size, void* d_ws, size_t ws_size,
                              hipStream_t stream) {
    const float* out = (const float*)d_in[0];
    const float* tgt = (const float*)d_in[1];
    float* W = (float*)d_ws;
    float* res = (float*)d_out;
    hipLaunchKernelGGL(fused_kernel, dim3(NBLK), dim3(256), 0, stream, out, tgt, W);
    hipLaunchKernelGGL(fin_kernel, dim3(1), dim3(256), 0, stream, W, res);
}

// Round 2
// 280.293 us; speedup vs baseline: 1.1835x; 1.0733x over previous
//
#include <hip/hip_runtime.h>

#define NB 32
#define NA 5
#define NC 80
#define NH 64
#define NW 64
#define MAXT 50
#define CH 85
#define HW (NH*NW)
#define BPB 40                 /* blocks per batch: NA*HW/512 (2 cells/thread) */
#define NBLK (NB*BPB)          /* 1280 */

__constant__ float c_aw[NA] = {42.3f/32.0f, 102.2f/32.0f, 161.8f/32.0f, 303.1f/32.0f, 359.6f/32.0f};
__constant__ float c_ah[NA] = {55.4f/32.0f, 128.3f/32.0f, 259.2f/32.0f, 154.9f/32.0f, 320.2f/32.0f};

__device__ __forceinline__ float sigm(float x) {
    return __builtin_amdgcn_rcpf(1.0f + __expf(-x));
}

// Fused region loss. Phase 1 reads targets DIRECTLY from global with uniform
// addresses (b, tt uniform) -> s_load + scalar-cache broadcast; no LDS in the
// hot loop (previous version was LDS-issue-bound: 5 ds_read broadcasts/iter).
// 2 cells per thread amortize the per-target uniform prep. Wave-uniform y-skip
// is exact: a screened-out target yields inter=0 -> candidate = -0.375*gw*gh
// <= -3.84 < -1 = m_init, so the max is unchanged.
__global__ __launch_bounds__(256) void fused_kernel(const float* __restrict__ out,
                                                    const float* __restrict__ tgt,
                                                    float* __restrict__ W) {
    const int blk = blockIdx.x;
    const int tid = threadIdx.x;
    const int b   = blk / BPB;            // uniform
    const int r   = blk - b*BPB;          // uniform
    const int a   = r >> 3;               // uniform; 8 blocks per (b,a)
    const int ji0 = ((r & 7) << 9) + tid; // cells ji0 and ji0+256 (8-row strip)
    const int i0  = ji0 & (NW-1);
    const int j0  = ji0 >> 6;

    // per-wave nv (uniform in SGPR, no barrier): cumprod(x != 0) first-zero cutoff
    const int lane = tid & 63;
    bool isz = true;
    if (lane < MAXT) isz = (tgt[(b*MAXT + lane)*5 + 1] == 0.0f);
    const int nv = __ffsll(__ballot(isz)) - 1;

    // ---- phase 1: base loss, 2 cells per thread ----
    const size_t base0 = (size_t)((b*NA + a)*CH)*HW + ji0;   // cell1 = +256
    const float ox0 = out[base0],        ox1 = out[base0+256];
    const float oy0 = out[base0+HW],     oy1 = out[base0+HW+256];
    const float ow0 = out[base0+2*HW],   ow1 = out[base0+2*HW+256];
    const float oh0 = out[base0+3*HW],   oh1 = out[base0+3*HW+256];
    const float oc0 = out[base0+4*HW],   oc1 = out[base0+4*HW+256];

    const float aw = c_aw[a], ah = c_ah[a];
    const float sx0 = sigm(ox0), sy0 = sigm(oy0), sc0 = sigm(oc0);
    const float sx1 = sigm(ox1), sy1 = sigm(oy1), sc1 = sigm(oc1);
    const float pw0 = __expf(ow0)*aw, ph0 = __expf(oh0)*ah;
    const float pw1 = __expf(ow1)*aw, ph1 = __expf(oh1)*ah;
    const float px0 = sx0 + (float)i0, py0 = sy0 + (float)j0;
    const float px1 = sx1 + (float)i0, py1 = sy1 + (float)(j0+4);
    const float pxl0 = px0 - 0.5f*pw0, pxh0 = px0 + 0.5f*pw0;
    const float pyl0 = py0 - 0.5f*ph0, pyh0 = py0 + 0.5f*ph0;
    const float pxl1 = px1 - 0.5f*pw1, pxh1 = px1 + 0.5f*pw1;
    const float pyl1 = py1 - 0.5f*ph1, pyh1 = py1 + 0.5f*ph1;
    const float pa0 = 0.375f*pw0*ph0;
    const float pa1 = 0.375f*pw1*ph1;

    float m0 = -1.0f, m1 = -1.0f;
    const float* __restrict__ tb = tgt + (size_t)b*MAXT*5;
    for (int tt = 0; tt < nv; tt++) {
        const int t5 = tt*5;
        // uniform addresses -> scalar loads (broadcast via K$, no LDS pipe)
        const float gy = tb[t5+2] * (float)NH;
        const float gh = tb[t5+4] * (float)NH;
        const float tyl = gy - 0.5f*gh;
        const float tyh = gy + 0.5f*gh;
        const float ih0 = fminf(pyh0, tyh) - fmaxf(pyl0, tyl);
        const float ih1 = fminf(pyh1, tyh) - fmaxf(pyl1, tyl);
        if (__any((ih0 > 0.0f) || (ih1 > 0.0f))) {
            const float gx = tb[t5+1] * (float)NW;
            const float gw = tb[t5+3] * (float)NW;
            const float txl = gx - 0.5f*gw;
            const float txh = gx + 0.5f*gw;
            const float ga  = 0.375f*(gw*gh);
            const float iw0 = fminf(pxh0, txh) - fmaxf(pxl0, txl);
            const float iw1 = fminf(pxh1, txh) - fmaxf(pxl1, txl);
            const float in0 = fmaxf(iw0, 0.f) * fmaxf(ih0, 0.f);
            const float in1 = fmaxf(iw1, 0.f) * fmaxf(ih1, 0.f);
            m0 = fmaxf(m0, in0 - ga);
            m1 = fmaxf(m1, in1 - ga);
        }
    }

    const float dx0 = sx0 - 0.5f, dy0 = sy0 - 0.5f;
    float v0 = dx0*dx0 + dy0*dy0 + ow0*ow0 + oh0*oh0;
    if (!(m0 > pa0)) v0 += sc0*sc0;
    const float dx1 = sx1 - 0.5f, dy1 = sy1 - 0.5f;
    float v1 = dx1*dx1 + dy1*dy1 + ow1*ow1 + oh1*oh1;
    if (!(m1 > pa1)) v1 += sc1*sc1;
    float v = (v0 + v1) * 0.5f;

    __shared__ float red[4];
    for (int off = 32; off > 0; off >>= 1) v += __shfl_down(v, off);
    if ((tid & 63) == 0) red[tid >> 6] = v;
    __syncthreads();
    float bsum = (tid == 0) ? (red[0] + red[1] + red[2] + red[3]) : 0.0f;

    // ---- phase 2: correction (first block of each batch only; block-uniform) ----
    __shared__ float sxl[MAXT], sxh[MAXT], syl[MAXT], syh[MAXT], sga[MAXT];
    __shared__ int   s_id[MAXT], s_eid[MAXT], s_ec[MAXT];
    __shared__ float s_tx[MAXT], s_ty[MAXT], s_tw[MAXT], s_th[MAXT], s_ti[MAXT];
    if (r == 0) {
        // 2a: per-target entry build (wave 0, lane = target)
        if (tid < 64 && tid < nv) {
            const float* p = tgt + (b*MAXT + tid)*5;
            const float gcls = p[0];
            const float gx = p[1] * (float)NW;
            const float gy = p[2] * (float)NH;
            const float gw = p[3] * (float)NW;
            const float gh = p[4] * (float)NH;
            sxl[tid] = gx - 0.5f*gw; sxh[tid] = gx + 0.5f*gw;
            syl[tid] = gy - 0.5f*gh; syh[tid] = gy + 0.5f*gh;
            sga[tid] = 0.375f*gw*gh;

            const float garea = gw * gh;
            float best = -1.0f; int bn = 0;
            #pragma unroll
            for (int n = 0; n < NA; n++) {
                float inter = fminf(gw, c_aw[n]) * fminf(gh, c_ah[n]);
                float uni = garea + c_aw[n]*c_ah[n] - inter;
                float rr = inter / uni;
                if (rr > best) { best = rr; bn = n; }   // first-max wins (argmax)
            }
            int gi = (int)gx; gi = gi < 0 ? 0 : (gi > NW-1 ? NW-1 : gi);
            int gj = (int)gy; gj = gj < 0 ? 0 : (gj > NH-1 ? NH-1 : gj);
            const float awb = c_aw[bn], ahb = c_ah[bn];

            const size_t gbase = (size_t)((b*NA + bn)*CH)*HW + gj*NW + gi;
            const float o0 = out[gbase];
            const float o1 = out[gbase + HW];
            const float o2 = out[gbase + 2*HW];
            const float o3 = out[gbase + 3*HW];
            const float ppx = sigm(o0) + (float)gi;
            const float ppy = sigm(o1) + (float)gj;
            const float ppw = __expf(o2) * awb;
            const float pph = __expf(o3) * ahb;
            const float iw = fminf(gx + 0.5f*gw, ppx + 0.5f*ppw) - fmaxf(gx - 0.5f*gw, ppx - 0.5f*ppw);
            const float ih = fminf(gy + 0.5f*gh, ppy + 0.5f*pph) - fmaxf(gy - 0.5f*gh, ppy - 0.5f*pph);
            const float inter = fmaxf(iw, 0.f) * fmaxf(ih, 0.f);
            const float tiou = inter / (garea + ppw*pph - inter);

            s_id[tid] = (bn*NH + gj)*NW + gi;
            s_tx[tid] = gx - (float)gi;
            s_ty[tid] = gy - (float)gj;
            s_tw[tid] = __logf(gw / awb);
            s_th[tid] = __logf(gh / ahb);
            s_ti[tid] = tiou;
            s_ec[tid] = (int)gcls;
        }
        __syncthreads();
        // parallel last-wins dedup (matches sequential .at[].set)
        if (tid < nv) {
            const int myid = s_id[tid];
            bool keep = true;
            for (int u = tid + 1; u < nv; u++)
                if (s_id[u] == myid) { keep = false; break; }
            s_eid[tid] = keep ? myid : -1;
        }
        __syncthreads();

        // 2b: 4 lanes per entry; channels strided by 4, register-resident.
        float acc = 0.0f;
        const int e = tid >> 2;
        const int q = tid & 3;
        if (e < nv) {
            const int id = s_eid[e];                 // uniform within the 4-lane group
            if (id >= 0) {
                const int ea  = id >> 12;
                const int eji = id & (HW-1);
                const int eii = eji & (NW-1);
                const int ejj = eji >> 6;
                const size_t eb = (size_t)((b*NA + ea)*CH)*HW + eji;
                const float cox = out[eb];
                const float coy = out[eb + HW];
                const float cow = out[eb + 2*HW];
                const float coh = out[eb + 3*HW];
                const float coc = out[eb + 4*HW];
                const float csx = sigm(cox), csy = sigm(coy), csc = sigm(coc);
                const float cpw = __expf(cow) * c_aw[ea];
                const float cph = __expf(coh) * c_ah[ea];
                const float cpx = csx + (float)eii, cpy = csy + (float)ejj;
                const float cxl = cpx - 0.5f*cpw, cxh = cpx + 0.5f*cpw;
                const float cyl = cpy - 0.5f*cph, cyh = cpy + 0.5f*cph;
                const float cpa = 0.375f * cpw * cph;

                // conf_mask0 recompute, nv-loop split across the 4 lanes
                float mm = -1.0f;
                for (int u = q; u < nv; u += 4) {
                    float iw = fminf(cxh, sxh[u]) - fmaxf(cxl, sxl[u]);
                    float ih = fminf(cyh, syh[u]) - fmaxf(cyl, syl[u]);
                    float inter = fmaxf(iw, 0.f) * fmaxf(ih, 0.f);
                    mm = fmaxf(mm, inter - sga[u]);
                }
                mm = fmaxf(mm, __shfl_xor(mm, 1));
                mm = fmaxf(mm, __shfl_xor(mm, 2));

                // logsumexp over 80 classes: 20 channels per lane, one global pass
                const float* lg = out + eb + 5*HW;
                float rch[20];
                #pragma unroll
                for (int k = 0; k < 20; k++) rch[k] = lg[(size_t)(q + 4*k)*HW];
                float mx = rch[0];
                #pragma unroll
                for (int k = 1; k < 20; k++) mx = fmaxf(mx, rch[k]);
                mx = fmaxf(mx, __shfl_xor(mx, 1));
                mx = fmaxf(mx, __shfl_xor(mx, 2));
                float s = 0.0f;
                #pragma unroll
                for (int k = 0; k < 20; k++) s += __expf(rch[k] - mx);
                s += __shfl_xor(s, 1);
                s += __shfl_xor(s, 2);

                if (q == 0) {
                    const float tx = s_tx[e], ty = s_ty[e], tw = s_tw[e], th = s_th[e], ti = s_ti[e];
                    const int cls = s_ec[e];
                    const float dxn = csx - tx, dxo = csx - 0.5f;
                    const float dyn = csy - ty, dyo = csy - 0.5f;
                    const float dwn = cow - tw, dhn = coh - th;
                    float d = dxn*dxn - dxo*dxo + dyn*dyn - dyo*dyo
                            + dwn*dwn - cow*cow + dhn*dhn - coh*coh;
                    float dc = 5.f*(csc - ti)*(csc - ti);
                    if (!(mm > cpa)) dc -= csc*csc;   // base had conf_mask0 * conf^2
                    d += dc;
                    acc += 0.5f * d;
                    acc += mx + __logf(s) - lg[(size_t)cls*HW];
                }
            }
        }
        for (int off = 32; off > 0; off >>= 1) acc += __shfl_down(acc, off);
        if ((tid & 63) == 0) red[tid >> 6] = acc;
        __syncthreads();
        if (tid == 0) bsum += red[0] + red[1] + red[2] + red[3];
    }

    if (tid == 0) W[blk] = bsum;   // partial per block; poison-safe (always written)
}

__global__ __launch_bounds__(256) void fin_kernel(const float* __restrict__ W,
                                                  float* __restrict__ res) {
    float s = 0.0f;
    for (int k = threadIdx.x; k < NBLK; k += 256) s += W[k];
    for (int off = 32; off > 0; off >>= 1) s += __shfl_down(s, off);
    __shared__ float red[4];
    if ((threadIdx.x & 63) == 0) red[threadIdx.x >> 6] = s;
    __syncthreads();
    if (threadIdx.x == 0) res[0] = red[0] + red[1] + red[2] + red[3];
}

extern "C" void kernel_launch(void* const* d_in, const int* in_sizes, int n_in,
                              void* d_out, int out_size, void* d_ws, size_t ws_size,
                              hipStream_t stream) {
    const float* out = (const float*)d_in[0];
    const float* tgt = (const float*)d_in[1];
    float* W = (float*)d_ws;
    float* res = (float*)d_out;
    hipLaunchKernelGGL(fused_kernel, dim3(NBLK), dim3(256), 0, stream, out, tgt, W);
    hipLaunchKernelGGL(fin_kernel, dim3(1), dim3(256), 0, stream, W, res);
}